// Round 1
// baseline (109.342 us; speedup 1.0000x reference)
//
#include <hip/hip_runtime.h>
#include <math.h>

#define SIZE   256
#define NFACES 256
#define NVERTS 1024

struct __align__(16) FaceData {
    float ax, ay, bx, by, cx, cy;     // 2D vertex positions
    float z0i, z1i, z2i;              // 1/z per vertex
    float u0x, u0y, u1x, u1y, u2x, u2y; // (uv*2-1)*z_inv per vertex
    float Asafe;
    float valid;                      // 1.0 / 0.0
    float _pad;
};

__global__ __launch_bounds__(256) void render_kernel(
    const float* __restrict__ vertices,  // (1024,3)
    const int*   __restrict__ faces,     // (256,3)
    const float* __restrict__ uv,        // (1024,2)
    const int*   __restrict__ uvfaces,   // (256,3)
    const float* __restrict__ uvmap,     // (3,256,256)
    float* __restrict__ out)             // (4,256,256)
{
#pragma clang fp contract(off)
    __shared__ FaceData fd[NFACES];
    __shared__ float red[256];

    const int t   = threadIdx.x;   // column j
    const int row = blockIdx.x;    // row i

    // ---- zinit = min over all vertex z (block-redundant, cheap) ----
    float m = 1e30f;
    for (int v = t; v < NVERTS; v += 256) m = fminf(m, vertices[3*v + 2]);
    red[t] = m;
    __syncthreads();
    for (int s = 128; s > 0; s >>= 1) {
        if (t < s) red[t] = fminf(red[t], red[t + s]);
        __syncthreads();
    }
    const float zinit = red[0];

    // ---- per-face preprocessing: thread t handles face t ----
    {
        const int f  = t;
        const int i0 = faces[3*f+0], i1 = faces[3*f+1], i2 = faces[3*f+2];
        const float ax = vertices[3*i0+0], ay = vertices[3*i0+1], az = vertices[3*i0+2];
        const float bx = vertices[3*i1+0], by = vertices[3*i1+1], bz = vertices[3*i1+2];
        const float cx = vertices[3*i2+0], cy = vertices[3*i2+1], cz = vertices[3*i2+2];
        // A = area2d(v0,v1,v2); same fp32 expression as face-normal z, so
        // cullmask & (A>=1e-9)  ==  (A >= 1e-9)
        const float A = (bx-ax)*(cy-ay) - (by-ay)*(cx-ax);
        const float z0i = 1.0f/az, z1i = 1.0f/bz, z2i = 1.0f/cz;
        const int j0 = uvfaces[3*f+0], j1 = uvfaces[3*f+1], j2 = uvfaces[3*f+2];
        FaceData d;
        d.ax = ax; d.ay = ay; d.bx = bx; d.by = by; d.cx = cx; d.cy = cy;
        d.z0i = z0i; d.z1i = z1i; d.z2i = z2i;
        d.u0x = (uv[2*j0+0]*2.0f - 1.0f) * z0i;
        d.u0y = (uv[2*j0+1]*2.0f - 1.0f) * z0i;
        d.u1x = (uv[2*j1+0]*2.0f - 1.0f) * z1i;
        d.u1y = (uv[2*j1+1]*2.0f - 1.0f) * z1i;
        d.u2x = (uv[2*j2+0]*2.0f - 1.0f) * z2i;
        d.u2y = (uv[2*j2+1]*2.0f - 1.0f) * z2i;
        d.Asafe = (fabsf(A) < 1e-9f) ? 1.0f : A;
        d.valid = (A >= 1e-9f) ? 1.0f : 0.0f;
        d._pad  = 0.0f;
        fd[f] = d;
    }
    __syncthreads();

    // pts[i,j] = (lin[j], lin[255-i]); linspace computed f64 -> f32 (numpy style)
    const float px = (float)(-1.0 + (double)t           * (2.0/255.0));
    const float py = (float)(-1.0 + (double)(255 - row) * (2.0/255.0));

    // ---- depth-test loop over faces: argmax (first-max) of score ----
    float best = -INFINITY;
    int   win  = 0;
    for (int f = 0; f < NFACES; ++f) {
        const FaceData &d = fd[f];
        const float pAB = (px - d.bx)*(d.ay - d.by) - (py - d.by)*(d.ax - d.bx);
        const float pCB = (px - d.cx)*(d.by - d.cy) - (py - d.cy)*(d.bx - d.cx);
        const float pCA = (px - d.ax)*(d.cy - d.ay) - (py - d.ay)*(d.cx - d.ax);
        if (pAB > 0.0f && pCB > 0.0f && pCA > 0.0f && d.valid > 0.5f) {
            const float w1 = pCB / d.Asafe;
            const float w2 = pCA / d.Asafe;
            const float w3 = (1.0f - w1) - w2;
            const float zp = (w1*d.z0i + w2*d.z1i) + w3*d.z2i;
            const float z  = 1.0f / zp;                // ptsZ
            if (z >= zinit && z > best) { best = z; win = f; }
        }
    }

    const bool  hit = (best > -INFINITY);
    const float hf  = hit ? 1.0f : 0.0f;
    float r0 = 0.0f, r1 = 0.0f, r2 = 0.0f;

    if (hit) {
        const FaceData &d = fd[win];
        const float pCB = (px - d.cx)*(d.by - d.cy) - (py - d.cy)*(d.bx - d.cx);
        const float pCA = (px - d.ax)*(d.cy - d.ay) - (py - d.ay)*(d.cx - d.ax);
        const float w1 = pCB / d.Asafe;
        const float w2 = pCA / d.Asafe;
        const float w3 = (1.0f - w1) - w2;
        const float p3 = (w1*d.u0x + w2*d.u1x) + w3*d.u2x;  // uv.x * zinv interp
        const float p4 = (w1*d.u0y + w2*d.u1y) + w3*d.u2y;  // uv.y * zinv interp
        const float p8 = (w1*d.z0i + w2*d.z1i) + w3*d.z2i;  // zinv interp
        const float Zw = 1.0f / p8;
        const float gx = p3 * Zw;
        const float gy = p4 * Zw;

        // bilinear_sample(uvmap, gx, gy), zero padding, W=H=256
        const float x = ((gx + 1.0f)*256.0f - 1.0f)*0.5f;
        const float y = ((gy + 1.0f)*256.0f - 1.0f)*0.5f;
        const float x0f = floorf(x), y0f = floorf(y);
        const float x1f = x0f + 1.0f, y1f = y0f + 1.0f;
        const float wx1 = x - x0f, wx0 = 1.0f - wx1;
        const float wy1 = y - y0f, wy0 = 1.0f - wy1;
        const float w00 = wx0*wy0, w10 = wx1*wy0, w01 = wx0*wy1, w11 = wx1*wy1;

        // corner order matches reference add order: (x0,y0)+(x1,y0)+(x0,y1)+(x1,y1)
        {
            const bool v = (x0f >= 0.0f) && (x0f <= 255.0f) && (y0f >= 0.0f) && (y0f <= 255.0f);
            const int ix = (int)fminf(fmaxf(x0f, 0.0f), 255.0f);
            const int iy = (int)fminf(fmaxf(y0f, 0.0f), 255.0f);
            const int o  = iy*256 + ix;
            const float g0 = v ? uvmap[o]          : 0.0f;
            const float g1 = v ? uvmap[65536 + o]  : 0.0f;
            const float g2 = v ? uvmap[131072 + o] : 0.0f;
            r0 = r0 + g0*w00; r1 = r1 + g1*w00; r2 = r2 + g2*w00;
        }
        {
            const bool v = (x1f >= 0.0f) && (x1f <= 255.0f) && (y0f >= 0.0f) && (y0f <= 255.0f);
            const int ix = (int)fminf(fmaxf(x1f, 0.0f), 255.0f);
            const int iy = (int)fminf(fmaxf(y0f, 0.0f), 255.0f);
            const int o  = iy*256 + ix;
            const float g0 = v ? uvmap[o]          : 0.0f;
            const float g1 = v ? uvmap[65536 + o]  : 0.0f;
            const float g2 = v ? uvmap[131072 + o] : 0.0f;
            r0 = r0 + g0*w10; r1 = r1 + g1*w10; r2 = r2 + g2*w10;
        }
        {
            const bool v = (x0f >= 0.0f) && (x0f <= 255.0f) && (y1f >= 0.0f) && (y1f <= 255.0f);
            const int ix = (int)fminf(fmaxf(x0f, 0.0f), 255.0f);
            const int iy = (int)fminf(fmaxf(y1f, 0.0f), 255.0f);
            const int o  = iy*256 + ix;
            const float g0 = v ? uvmap[o]          : 0.0f;
            const float g1 = v ? uvmap[65536 + o]  : 0.0f;
            const float g2 = v ? uvmap[131072 + o] : 0.0f;
            r0 = r0 + g0*w01; r1 = r1 + g1*w01; r2 = r2 + g2*w01;
        }
        {
            const bool v = (x1f >= 0.0f) && (x1f <= 255.0f) && (y1f >= 0.0f) && (y1f <= 255.0f);
            const int ix = (int)fminf(fmaxf(x1f, 0.0f), 255.0f);
            const int iy = (int)fminf(fmaxf(y1f, 0.0f), 255.0f);
            const int o  = iy*256 + ix;
            const float g0 = v ? uvmap[o]          : 0.0f;
            const float g1 = v ? uvmap[65536 + o]  : 0.0f;
            const float g2 = v ? uvmap[131072 + o] : 0.0f;
            r0 = r0 + g0*w11; r1 = r1 + g1*w11; r2 = r2 + g2*w11;
        }
    }

    const int pix = row*256 + t;
    out[           pix] = r0*hf;
    out[ 65536 +   pix] = r1*hf;
    out[131072 +   pix] = r2*hf;
    out[196608 +   pix] = hf;
}

extern "C" void kernel_launch(void* const* d_in, const int* in_sizes, int n_in,
                              void* d_out, int out_size, void* d_ws, size_t ws_size,
                              hipStream_t stream) {
    const float* vertices = (const float*)d_in[0];
    const int*   faces    = (const int*)  d_in[1];
    const float* uv       = (const float*)d_in[2];
    const int*   uvfaces  = (const int*)  d_in[3];
    const float* uvmap    = (const float*)d_in[4];
    float*       out      = (float*)d_out;

    render_kernel<<<SIZE, SIZE, 0, stream>>>(vertices, faces, uv, uvfaces, uvmap, out);
}

// Round 2
// 85.371 us; speedup vs baseline: 1.2808x; 1.2808x over previous
//
#include <hip/hip_runtime.h>
#include <math.h>

#define SIZE   256
#define NFACES 256
#define NVERTS 1024
#define NSPLIT 4
#define FPG    (NFACES / NSPLIT)   // 64 faces per group

struct __align__(16) FaceData {
    float ax, ay, bx, by, cx, cy;       // 2D vertex positions
    float z0i, z1i, z2i;                // 1/z per vertex
    float u0x, u0y, u1x, u1y, u2x, u2y; // (uv*2-1)*z_inv per vertex
    float Asafe;
    float valid;                        // 1.0 / 0.0
    float _pad;
};

// block = 1024 threads (16 waves): group g = tid>>8 tests faces [64g,64g+64)
// for column tid&255 of row blockIdx.x; LDS combine keeps argmax first-max
// semantics (ascending g, strict >).
__global__ __launch_bounds__(1024) void render_kernel(
    const float* __restrict__ vertices,  // (1024,3)
    const int*   __restrict__ faces,     // (256,3)
    const float* __restrict__ uv,        // (1024,2)
    const int*   __restrict__ uvfaces,   // (256,3)
    const float* __restrict__ uvmap,     // (3,256,256)
    float* __restrict__ out)             // (4,256,256)
{
#pragma clang fp contract(off)
    __shared__ FaceData fd[NFACES];
    __shared__ float red[1024];
    __shared__ float sh_best[NSPLIT][256];
    __shared__ int   sh_win [NSPLIT][256];

    const int t   = threadIdx.x;
    const int col = t & 255;
    const int grp = t >> 8;
    const int row = blockIdx.x;

    // ---- zinit = min over all 1024 vertex z ----
    red[t] = vertices[3*t + 2];
    __syncthreads();
    for (int s = 512; s > 0; s >>= 1) {
        if (t < s) red[t] = fminf(red[t], red[t + s]);
        __syncthreads();
    }
    const float zinit = red[0];

    // ---- per-face preprocessing: thread t < 256 handles face t ----
    if (t < NFACES) {
        const int f  = t;
        const int i0 = faces[3*f+0], i1 = faces[3*f+1], i2 = faces[3*f+2];
        const float ax = vertices[3*i0+0], ay = vertices[3*i0+1], az = vertices[3*i0+2];
        const float bx = vertices[3*i1+0], by = vertices[3*i1+1], bz = vertices[3*i1+2];
        const float cx = vertices[3*i2+0], cy = vertices[3*i2+1], cz = vertices[3*i2+2];
        // A = area2d; same fp32 expression as face-normal z, so
        // cullmask & (A>=1e-9)  ==  (A >= 1e-9)
        const float A = (bx-ax)*(cy-ay) - (by-ay)*(cx-ax);
        const float z0i = 1.0f/az, z1i = 1.0f/bz, z2i = 1.0f/cz;
        const int j0 = uvfaces[3*f+0], j1 = uvfaces[3*f+1], j2 = uvfaces[3*f+2];
        FaceData d;
        d.ax = ax; d.ay = ay; d.bx = bx; d.by = by; d.cx = cx; d.cy = cy;
        d.z0i = z0i; d.z1i = z1i; d.z2i = z2i;
        d.u0x = (uv[2*j0+0]*2.0f - 1.0f) * z0i;
        d.u0y = (uv[2*j0+1]*2.0f - 1.0f) * z0i;
        d.u1x = (uv[2*j1+0]*2.0f - 1.0f) * z1i;
        d.u1y = (uv[2*j1+1]*2.0f - 1.0f) * z1i;
        d.u2x = (uv[2*j2+0]*2.0f - 1.0f) * z2i;
        d.u2y = (uv[2*j2+1]*2.0f - 1.0f) * z2i;
        d.Asafe = (fabsf(A) < 1e-9f) ? 1.0f : A;
        d.valid = (A >= 1e-9f) ? 1.0f : 0.0f;
        d._pad  = 0.0f;
        fd[f] = d;
    }
    __syncthreads();

    // pts[i,j] = (lin[j], lin[255-i]); linspace computed f64 -> f32 (numpy style)
    const float px = (float)(-1.0 + (double)col         * (2.0/255.0));
    const float py = (float)(-1.0 + (double)(255 - row) * (2.0/255.0));

    // ---- depth-test over this group's 64 faces ----
    float best = -INFINITY;
    int   win  = 0;
    const int f0 = grp * FPG;
    for (int f = f0; f < f0 + FPG; ++f) {
        const FaceData &d = fd[f];
        const float pAB = (px - d.bx)*(d.ay - d.by) - (py - d.by)*(d.ax - d.bx);
        const float pCB = (px - d.cx)*(d.by - d.cy) - (py - d.cy)*(d.bx - d.cx);
        const float pCA = (px - d.ax)*(d.cy - d.ay) - (py - d.ay)*(d.cx - d.ax);
        if (pAB > 0.0f && pCB > 0.0f && pCA > 0.0f && d.valid > 0.5f) {
            const float w1 = pCB / d.Asafe;
            const float w2 = pCA / d.Asafe;
            const float w3 = (1.0f - w1) - w2;
            const float zp = (w1*d.z0i + w2*d.z1i) + w3*d.z2i;
            const float z  = 1.0f / zp;                // ptsZ
            if (z >= zinit && z > best) { best = z; win = f; }
        }
    }
    sh_best[grp][col] = best;
    sh_win [grp][col] = win;
    __syncthreads();

    // ---- combine 4 groups + epilogue: threads 0..255 (one per column) ----
    if (t < 256) {
        best = -INFINITY; win = 0;
        for (int g = 0; g < NSPLIT; ++g) {          // ascending g + strict >
            const float z = sh_best[g][t];          //  = first-max (lowest face idx)
            if (z > best) { best = z; win = sh_win[g][t]; }
        }

        const bool  hit = (best > -INFINITY);
        const float hf  = hit ? 1.0f : 0.0f;
        float r0 = 0.0f, r1 = 0.0f, r2 = 0.0f;

        if (hit) {
            const FaceData &d = fd[win];
            const float pCB = (px - d.cx)*(d.by - d.cy) - (py - d.cy)*(d.bx - d.cx);
            const float pCA = (px - d.ax)*(d.cy - d.ay) - (py - d.ay)*(d.cx - d.ax);
            const float w1 = pCB / d.Asafe;
            const float w2 = pCA / d.Asafe;
            const float w3 = (1.0f - w1) - w2;
            const float p3 = (w1*d.u0x + w2*d.u1x) + w3*d.u2x;  // uv.x * zinv interp
            const float p4 = (w1*d.u0y + w2*d.u1y) + w3*d.u2y;  // uv.y * zinv interp
            const float p8 = (w1*d.z0i + w2*d.z1i) + w3*d.z2i;  // zinv interp
            const float Zw = 1.0f / p8;
            const float gx = p3 * Zw;
            const float gy = p4 * Zw;

            // bilinear_sample(uvmap, gx, gy), zero padding, W=H=256
            const float x = ((gx + 1.0f)*256.0f - 1.0f)*0.5f;
            const float y = ((gy + 1.0f)*256.0f - 1.0f)*0.5f;
            const float x0f = floorf(x), y0f = floorf(y);
            const float x1f = x0f + 1.0f, y1f = y0f + 1.0f;
            const float wx1 = x - x0f, wx0 = 1.0f - wx1;
            const float wy1 = y - y0f, wy0 = 1.0f - wy1;
            const float w00 = wx0*wy0, w10 = wx1*wy0, w01 = wx0*wy1, w11 = wx1*wy1;

            // corner order matches reference add order
            {
                const bool v = (x0f >= 0.0f) && (x0f <= 255.0f) && (y0f >= 0.0f) && (y0f <= 255.0f);
                const int ix = (int)fminf(fmaxf(x0f, 0.0f), 255.0f);
                const int iy = (int)fminf(fmaxf(y0f, 0.0f), 255.0f);
                const int o  = iy*256 + ix;
                const float g0 = v ? uvmap[o]          : 0.0f;
                const float g1 = v ? uvmap[65536 + o]  : 0.0f;
                const float g2 = v ? uvmap[131072 + o] : 0.0f;
                r0 = r0 + g0*w00; r1 = r1 + g1*w00; r2 = r2 + g2*w00;
            }
            {
                const bool v = (x1f >= 0.0f) && (x1f <= 255.0f) && (y0f >= 0.0f) && (y0f <= 255.0f);
                const int ix = (int)fminf(fmaxf(x1f, 0.0f), 255.0f);
                const int iy = (int)fminf(fmaxf(y0f, 0.0f), 255.0f);
                const int o  = iy*256 + ix;
                const float g0 = v ? uvmap[o]          : 0.0f;
                const float g1 = v ? uvmap[65536 + o]  : 0.0f;
                const float g2 = v ? uvmap[131072 + o] : 0.0f;
                r0 = r0 + g0*w10; r1 = r1 + g1*w10; r2 = r2 + g2*w10;
            }
            {
                const bool v = (x0f >= 0.0f) && (x0f <= 255.0f) && (y1f >= 0.0f) && (y1f <= 255.0f);
                const int ix = (int)fminf(fmaxf(x0f, 0.0f), 255.0f);
                const int iy = (int)fminf(fmaxf(y1f, 0.0f), 255.0f);
                const int o  = iy*256 + ix;
                const float g0 = v ? uvmap[o]          : 0.0f;
                const float g1 = v ? uvmap[65536 + o]  : 0.0f;
                const float g2 = v ? uvmap[131072 + o] : 0.0f;
                r0 = r0 + g0*w01; r1 = r1 + g1*w01; r2 = r2 + g2*w01;
            }
            {
                const bool v = (x1f >= 0.0f) && (x1f <= 255.0f) && (y1f >= 0.0f) && (y1f <= 255.0f);
                const int ix = (int)fminf(fmaxf(x1f, 0.0f), 255.0f);
                const int iy = (int)fminf(fmaxf(y1f, 0.0f), 255.0f);
                const int o  = iy*256 + ix;
                const float g0 = v ? uvmap[o]          : 0.0f;
                const float g1 = v ? uvmap[65536 + o]  : 0.0f;
                const float g2 = v ? uvmap[131072 + o] : 0.0f;
                r0 = r0 + g0*w11; r1 = r1 + g1*w11; r2 = r2 + g2*w11;
            }
        }

        const int pix = row*256 + t;
        out[           pix] = r0*hf;
        out[ 65536 +   pix] = r1*hf;
        out[131072 +   pix] = r2*hf;
        out[196608 +   pix] = hf;
    }
}

extern "C" void kernel_launch(void* const* d_in, const int* in_sizes, int n_in,
                              void* d_out, int out_size, void* d_ws, size_t ws_size,
                              hipStream_t stream) {
    const float* vertices = (const float*)d_in[0];
    const int*   faces    = (const int*)  d_in[1];
    const float* uv       = (const float*)d_in[2];
    const int*   uvfaces  = (const int*)  d_in[3];
    const float* uvmap    = (const float*)d_in[4];
    float*       out      = (float*)d_out;

    render_kernel<<<SIZE, 1024, 0, stream>>>(vertices, faces, uv, uvfaces, uvmap, out);
}

// Round 3
// 75.308 us; speedup vs baseline: 1.4519x; 1.1336x over previous
//
#include <hip/hip_runtime.h>
#include <math.h>

#define SIZE   256
#define NFACES 256
#define NVERTS 1024
#define NSPLIT 4

struct __align__(16) FaceData {
    float ax, ay, bx, by, cx, cy;       // 2D vertex positions
    float z0i, z1i, z2i;                // 1/z per vertex
    float u0x, u0y, u1x, u1y, u2x, u2y; // (uv*2-1)*z_inv per vertex
    float A;                            // area2d; == Asafe since A >= 1e-9 for kept faces
};  // 16 floats = 64 B

// block = 1024 threads (16 waves), one block per image row.
// Phase 1: threads 0..255 preprocess face t, cull back-facing (A<1e-9 => cover
//   false exactly) and row-reject by y-bbox with 1e-4 margin (fp edge noise is
//   <=~5e-7*scale, so a >=1e-4-outside point can never test covered in the
//   reference fp either). Stable ballot-compaction keeps ascending face order,
//   preserving argmax first-max tie-break.
// Phase 2: group g = tid>>8 tests its contiguous chunk of the compacted list
//   for column tid&255; LDS combine (ascending g, strict >) picks the winner.
__global__ __launch_bounds__(1024) void render_kernel(
    const float* __restrict__ vertices,  // (1024,3)
    const int*   __restrict__ faces,     // (256,3)
    const float* __restrict__ uv,        // (1024,2)
    const int*   __restrict__ uvfaces,   // (256,3)
    const float* __restrict__ uvmap,     // (3,256,256)
    float* __restrict__ out)             // (4,256,256)
{
#pragma clang fp contract(off)
    __shared__ FaceData fd[NFACES];
    __shared__ float sh_best[NSPLIT][256];
    __shared__ int   sh_win [NSPLIT][256];
    __shared__ float wred[16];
    __shared__ int   wcnt[4];
    __shared__ int   s_nv;

    const int t    = threadIdx.x;
    const int lane = t & 63;
    const int wv   = t >> 6;    // wave id 0..15
    const int col  = t & 255;
    const int grp  = t >> 8;    // 0..3
    const int row  = blockIdx.x;

    // pts[i,j] = (lin[j], lin[255-i]); linspace computed f64 -> f32 (numpy style)
    const float px = (float)(-1.0 + (double)col         * (2.0/255.0));
    const float py = (float)(-1.0 + (double)(255 - row) * (2.0/255.0));

    // ---- zinit partial: wave-level min of one vertex z per thread ----
    {
        float m = vertices[3*t + 2];
        for (int off = 32; off > 0; off >>= 1)
            m = fminf(m, __shfl_down(m, off));
        if (lane == 0) wred[wv] = m;
    }

    // ---- per-face prep in registers: thread t < 256 handles face t ----
    FaceData d;
    bool keep = false;
    unsigned long long bmask = 0ull;
    int rank = 0;
    if (t < NFACES) {
        const int f  = t;
        const int i0 = faces[3*f+0], i1 = faces[3*f+1], i2 = faces[3*f+2];
        const float ax = vertices[3*i0+0], ay = vertices[3*i0+1], az = vertices[3*i0+2];
        const float bx = vertices[3*i1+0], by = vertices[3*i1+1], bz = vertices[3*i1+2];
        const float cx = vertices[3*i2+0], cy = vertices[3*i2+1], cz = vertices[3*i2+2];
        // A = area2d; same fp32 expression as face-normal z, so
        // cullmask & (A>=1e-9)  ==  (A >= 1e-9);  A>=1e-9 also => Asafe==A
        const float A = (bx-ax)*(cy-ay) - (by-ay)*(cx-ax);
        const float ymin = fminf(fminf(ay, by), cy);
        const float ymax = fmaxf(fmaxf(ay, by), cy);
        keep = (A >= 1e-9f) && (py > ymin - 1e-4f) && (py < ymax + 1e-4f);
        bmask = __ballot(keep);
        rank  = __popcll(bmask & ((1ull << lane) - 1ull));
        if (lane == 0) wcnt[wv] = (int)__popcll(bmask);
        if (keep) {
            const float z0i = 1.0f/az, z1i = 1.0f/bz, z2i = 1.0f/cz;
            const int j0 = uvfaces[3*f+0], j1 = uvfaces[3*f+1], j2 = uvfaces[3*f+2];
            d.ax = ax; d.ay = ay; d.bx = bx; d.by = by; d.cx = cx; d.cy = cy;
            d.z0i = z0i; d.z1i = z1i; d.z2i = z2i;
            d.u0x = (uv[2*j0+0]*2.0f - 1.0f) * z0i;
            d.u0y = (uv[2*j0+1]*2.0f - 1.0f) * z0i;
            d.u1x = (uv[2*j1+0]*2.0f - 1.0f) * z1i;
            d.u1y = (uv[2*j1+1]*2.0f - 1.0f) * z1i;
            d.u2x = (uv[2*j2+0]*2.0f - 1.0f) * z2i;
            d.u2y = (uv[2*j2+1]*2.0f - 1.0f) * z2i;
            d.A = A;
        }
    }
    __syncthreads();   // wred + wcnt published

    float zinit;
    {
        float mm = wred[0];
        #pragma unroll
        for (int i = 1; i < 16; ++i) mm = fminf(mm, wred[i]);
        zinit = mm;    // every thread computes; avoids another barrier
    }

    if (t < NFACES) {
        int base = 0;
        #pragma unroll
        for (int w = 0; w < 4; ++w) if (w < wv) base += wcnt[w];
        if (keep) fd[base + rank] = d;
        if (t == 0) s_nv = wcnt[0] + wcnt[1] + wcnt[2] + wcnt[3];
    }
    __syncthreads();   // fd + s_nv published

    // ---- depth-test over this group's chunk of the compacted list ----
    const int nv = s_nv;
    const int cs = (nv + NSPLIT - 1) / NSPLIT;
    int f0 = grp * cs;       if (f0 > nv) f0 = nv;
    int f1 = f0 + cs;        if (f1 > nv) f1 = nv;

    float best = -INFINITY;
    int   win  = 0;
    for (int f = f0; f < f1; ++f) {
        const FaceData &c = fd[f];
        const float pAB = (px - c.bx)*(c.ay - c.by) - (py - c.by)*(c.ax - c.bx);
        const float pCB = (px - c.cx)*(c.by - c.cy) - (py - c.cy)*(c.bx - c.cx);
        const float pCA = (px - c.ax)*(c.cy - c.ay) - (py - c.ay)*(c.cx - c.ax);
        if (pAB > 0.0f && pCB > 0.0f && pCA > 0.0f) {
            const float w1 = pCB / c.A;
            const float w2 = pCA / c.A;
            const float w3 = (1.0f - w1) - w2;
            const float zp = (w1*c.z0i + w2*c.z1i) + w3*c.z2i;
            const float z  = 1.0f / zp;                // ptsZ
            if (z >= zinit && z > best) { best = z; win = f; }
        }
    }
    sh_best[grp][col] = best;
    sh_win [grp][col] = win;
    __syncthreads();

    // ---- combine 4 groups + epilogue: threads 0..255 (one per column) ----
    if (t < 256) {
        best = -INFINITY; win = 0;
        #pragma unroll
        for (int g = 0; g < NSPLIT; ++g) {          // ascending g + strict >
            const float z = sh_best[g][t];          //  = first-max (lowest face idx)
            if (z > best) { best = z; win = sh_win[g][t]; }
        }

        const bool  hit = (best > -INFINITY);
        const float hf  = hit ? 1.0f : 0.0f;
        float r0 = 0.0f, r1 = 0.0f, r2 = 0.0f;

        if (hit) {
            const FaceData &c = fd[win];
            const float pCB = (px - c.cx)*(c.by - c.cy) - (py - c.cy)*(c.bx - c.cx);
            const float pCA = (px - c.ax)*(c.cy - c.ay) - (py - c.ay)*(c.cx - c.ax);
            const float w1 = pCB / c.A;
            const float w2 = pCA / c.A;
            const float w3 = (1.0f - w1) - w2;
            const float p3 = (w1*c.u0x + w2*c.u1x) + w3*c.u2x;  // uv.x * zinv interp
            const float p4 = (w1*c.u0y + w2*c.u1y) + w3*c.u2y;  // uv.y * zinv interp
            const float p8 = (w1*c.z0i + w2*c.z1i) + w3*c.z2i;  // zinv interp
            const float Zw = 1.0f / p8;
            const float gx = p3 * Zw;
            const float gy = p4 * Zw;

            // bilinear_sample(uvmap, gx, gy), zero padding, W=H=256
            const float x = ((gx + 1.0f)*256.0f - 1.0f)*0.5f;
            const float y = ((gy + 1.0f)*256.0f - 1.0f)*0.5f;
            const float x0f = floorf(x), y0f = floorf(y);
            const float x1f = x0f + 1.0f, y1f = y0f + 1.0f;
            const float wx1 = x - x0f, wx0 = 1.0f - wx1;
            const float wy1 = y - y0f, wy0 = 1.0f - wy1;
            const float w00 = wx0*wy0, w10 = wx1*wy0, w01 = wx0*wy1, w11 = wx1*wy1;

            // corner order matches reference add order
            {
                const bool v = (x0f >= 0.0f) && (x0f <= 255.0f) && (y0f >= 0.0f) && (y0f <= 255.0f);
                const int ix = (int)fminf(fmaxf(x0f, 0.0f), 255.0f);
                const int iy = (int)fminf(fmaxf(y0f, 0.0f), 255.0f);
                const int o  = iy*256 + ix;
                const float g0 = v ? uvmap[o]          : 0.0f;
                const float g1 = v ? uvmap[65536 + o]  : 0.0f;
                const float g2 = v ? uvmap[131072 + o] : 0.0f;
                r0 = r0 + g0*w00; r1 = r1 + g1*w00; r2 = r2 + g2*w00;
            }
            {
                const bool v = (x1f >= 0.0f) && (x1f <= 255.0f) && (y0f >= 0.0f) && (y0f <= 255.0f);
                const int ix = (int)fminf(fmaxf(x1f, 0.0f), 255.0f);
                const int iy = (int)fminf(fmaxf(y0f, 0.0f), 255.0f);
                const int o  = iy*256 + ix;
                const float g0 = v ? uvmap[o]          : 0.0f;
                const float g1 = v ? uvmap[65536 + o]  : 0.0f;
                const float g2 = v ? uvmap[131072 + o] : 0.0f;
                r0 = r0 + g0*w10; r1 = r1 + g1*w10; r2 = r2 + g2*w10;
            }
            {
                const bool v = (x0f >= 0.0f) && (x0f <= 255.0f) && (y1f >= 0.0f) && (y1f <= 255.0f);
                const int ix = (int)fminf(fmaxf(x0f, 0.0f), 255.0f);
                const int iy = (int)fminf(fmaxf(y1f, 0.0f), 255.0f);
                const int o  = iy*256 + ix;
                const float g0 = v ? uvmap[o]          : 0.0f;
                const float g1 = v ? uvmap[65536 + o]  : 0.0f;
                const float g2 = v ? uvmap[131072 + o] : 0.0f;
                r0 = r0 + g0*w01; r1 = r1 + g1*w01; r2 = r2 + g2*w01;
            }
            {
                const bool v = (x1f >= 0.0f) && (x1f <= 255.0f) && (y1f >= 0.0f) && (y1f <= 255.0f);
                const int ix = (int)fminf(fmaxf(x1f, 0.0f), 255.0f);
                const int iy = (int)fminf(fmaxf(y1f, 0.0f), 255.0f);
                const int o  = iy*256 + ix;
                const float g0 = v ? uvmap[o]          : 0.0f;
                const float g1 = v ? uvmap[65536 + o]  : 0.0f;
                const float g2 = v ? uvmap[131072 + o] : 0.0f;
                r0 = r0 + g0*w11; r1 = r1 + g1*w11; r2 = r2 + g2*w11;
            }
        }

        const int pix = row*256 + t;
        out[           pix] = r0*hf;
        out[ 65536 +   pix] = r1*hf;
        out[131072 +   pix] = r2*hf;
        out[196608 +   pix] = hf;
    }
}

extern "C" void kernel_launch(void* const* d_in, const int* in_sizes, int n_in,
                              void* d_out, int out_size, void* d_ws, size_t ws_size,
                              hipStream_t stream) {
    const float* vertices = (const float*)d_in[0];
    const int*   faces    = (const int*)  d_in[1];
    const float* uv       = (const float*)d_in[2];
    const int*   uvfaces  = (const int*)  d_in[3];
    const float* uvmap    = (const float*)d_in[4];
    float*       out      = (float*)d_out;

    render_kernel<<<SIZE, 1024, 0, stream>>>(vertices, faces, uv, uvfaces, uvmap, out);
}